// Round 2
// baseline (6628.662 us; speedup 1.0000x reference)
//
#include <hip/hip_runtime.h>
#include <hip/hip_bf16.h>

// Problem: 2-layer LSTM (T=1024, B=512, IN=20, H1=128, H2=64) + linear head OUT=3.
// KEY: reference takes h2[:, -1, :] => only batch element 511 matters.
// Single-CU sequential scan with all recurrent weights resident in VGPRs.
//
// Round-2 fix: __launch_bounds__(512,2) was interpreted as 2 blocks/CU ->
// 128-VGPR cap -> 96 regs of weights spilled to scratch, reloaded every step
// (~200KB/step => 6.6us/step). Pin occupancy to exactly 2 waves/EU so the
// 256-VGPR budget holds the full 224-reg weight set.

#define T_STEPS 1024
#define BATCH   512
#define IN_F    20
#define H1_     128
#define H2_     64
#define OUT_F   3
#define G1_     (4*H1_)   // 512 layer-1 gates
#define G2_     (4*H2_)   // 256 layer-2 gates

__device__ __forceinline__ float sigmoidf_(float x) {
    return 1.0f / (1.0f + __expf(-x));
}
// tanh(x) = 1 - 2/(exp(2x)+1); stable at +-inf via exp overflow->inf / underflow->0
__device__ __forceinline__ float tanhf_(float x) {
    return 1.0f - 2.0f / (__expf(2.0f * x) + 1.0f);
}

// ---------------- Kernel A: x-projection for batch row 511 -------------------
// xp1[t][g] = sum_i x[t,511,i] * W_ih0[g,i] + b_ih0[g] + b_hh0[g]
__global__ void xproj_kernel(const float* __restrict__ x,
                             const float* __restrict__ W_ih0,
                             const float* __restrict__ b_ih0,
                             const float* __restrict__ b_hh0,
                             float* __restrict__ xp1)
{
    const int t = blockIdx.x;
    const int g = threadIdx.x;
    const float* xr = x + ((size_t)t * BATCH + (BATCH - 1)) * IN_F;
    const float* w  = W_ih0 + g * IN_F;
    float acc = b_ih0[g] + b_hh0[g];
#pragma unroll
    for (int i = 0; i < IN_F; ++i) acc = fmaf(xr[i], w[i], acc);
    xp1[t * G1_ + g] = acc;
}

// ---------------- Kernel B: sequential 2-layer LSTM scan, 1 block ------------
// 512 threads (8 waves), exactly 2 waves/EU => 256-VGPR budget. Per thread:
//   wa[32]  : float4, W_hh0 row tid            (128 VGPRs)
//   w2[24]  : float4, layer-2 weight slice     ( 96 VGPRs)
//     tid <  256: W_ih1[o][0:96], o = tid
//     tid >= 256: W_ih1[o][96:128] (8) + W_hh1[o][0:64] (16), o = tid-256
// State: h1/h2 in LDS; c1 in reg of thread j<128; c2 in reg of thread j<64.
__global__ __attribute__((amdgpu_flat_work_group_size(512, 512),
                          amdgpu_waves_per_eu(2, 2)))
void lstm_seq_kernel(const float* __restrict__ xp1,
                     const float* __restrict__ W_hh0,
                     const float* __restrict__ W_ih1,
                     const float* __restrict__ W_hh1,
                     const float* __restrict__ b_ih1,
                     const float* __restrict__ b_hh1,
                     float* __restrict__ h2seq)
{
    const int tid = threadIdx.x;

    __shared__ float4 sh1[H1_ / 4];   // h1[128]
    __shared__ float4 sh2[H2_ / 4];   // h2[64]
    __shared__ float  sg1[G1_];       // activated layer-1 gates
    __shared__ float  sp2[2 * G2_];   // layer-2 gate partial sums

    // ---- load resident weights into registers (fully unrolled => VGPRs) ----
    float4 wa[32];
    {
        const float4* pa = (const float4*)(W_hh0 + tid * H1_);
#pragma unroll
        for (int k = 0; k < 32; ++k) wa[k] = pa[k];
    }
    float4 w2[24];
    float  bias2 = 0.0f;
    if (tid < G2_) {
        const float4* p = (const float4*)(W_ih1 + tid * H1_);
#pragma unroll
        for (int k = 0; k < 24; ++k) w2[k] = p[k];
        bias2 = b_ih1[tid] + b_hh1[tid];
    } else {
        const int o = tid - G2_;
        const float4* p = (const float4*)(W_ih1 + o * H1_ + 96);
#pragma unroll
        for (int k = 0; k < 8; ++k) w2[k] = p[k];
        const float4* q = (const float4*)(W_hh1 + o * H2_);
#pragma unroll
        for (int k = 0; k < 16; ++k) w2[8 + k] = q[k];
    }

    // ---- init state ----
    if (tid < H1_ / 4) sh1[tid] = float4{0, 0, 0, 0};
    if (tid < H2_ / 4) sh2[tid] = float4{0, 0, 0, 0};
    float c1 = 0.0f;       // owned by tid < 128
    float c2 = 0.0f;       // owned by tid < 64
    float hh1_part = 0.0f; // owned by tid >= 256
    __syncthreads();

    float xp_next = xp1[tid];   // prefetch t=0

    for (int t = 0; t < T_STEPS; ++t) {
        const float xp_cur = xp_next;
        {   // branchless prefetch of next step's x-projection (hides HBM latency)
            const int tn = (t + 1 < T_STEPS) ? (t + 1) : (T_STEPS - 1);
            xp_next = xp1[tn * G1_ + tid];
        }

        // ---- P1: layer-1 gate tid = xp + W_hh0[tid] . h1 , activated ----
        float4 a4 = {0, 0, 0, 0};
#pragma unroll
        for (int k = 0; k < 32; ++k) {
            const float4 h4 = sh1[k];
            a4.x = fmaf(wa[k].x, h4.x, a4.x);
            a4.y = fmaf(wa[k].y, h4.y, a4.y);
            a4.z = fmaf(wa[k].z, h4.z, a4.z);
            a4.w = fmaf(wa[k].w, h4.w, a4.w);
        }
        const float gate = xp_cur + ((a4.x + a4.y) + (a4.z + a4.w));
        // gates order i,f,g,o : i,f,o -> sigmoid ; g -> tanh
        const float act = (tid < 2 * H1_ || tid >= 3 * H1_) ? sigmoidf_(gate)
                                                            : tanhf_(gate);
        sg1[tid] = act;
        __syncthreads();

        // ---- P2: layer-1 pointwise (tid<128) ; overlap: W_hh1 . h2_old (tid>=256)
        if (tid < H1_) {
            const float iv = sg1[tid];
            const float fv = sg1[H1_ + tid];
            const float gv = sg1[2 * H1_ + tid];
            const float ov = sg1[3 * H1_ + tid];
            c1 = fmaf(fv, c1, iv * gv);
            const float h = ov * tanhf_(c1);
            ((float*)sh1)[tid] = h;
        } else if (tid >= G2_) {
            float4 s4 = {0, 0, 0, 0};
#pragma unroll
            for (int k = 0; k < 16; ++k) {
                const float4 h4 = sh2[k];
                s4.x = fmaf(w2[8 + k].x, h4.x, s4.x);
                s4.y = fmaf(w2[8 + k].y, h4.y, s4.y);
                s4.z = fmaf(w2[8 + k].z, h4.z, s4.z);
                s4.w = fmaf(w2[8 + k].w, h4.w, s4.w);
            }
            hh1_part = (s4.x + s4.y) + (s4.z + s4.w);
        }
        __syncthreads();

        // ---- P3: layer-2 gate partials over h1_new ----
        float p2v;
        if (tid < G2_) {
            float4 a = {0, 0, 0, 0};
#pragma unroll
            for (int k = 0; k < 24; ++k) {
                const float4 h4 = sh1[k];
                a.x = fmaf(w2[k].x, h4.x, a.x);
                a.y = fmaf(w2[k].y, h4.y, a.y);
                a.z = fmaf(w2[k].z, h4.z, a.z);
                a.w = fmaf(w2[k].w, h4.w, a.w);
            }
            p2v = bias2 + ((a.x + a.y) + (a.z + a.w));
        } else {
            float4 a = {0, 0, 0, 0};
#pragma unroll
            for (int k = 0; k < 8; ++k) {
                const float4 h4 = sh1[24 + k];
                a.x = fmaf(w2[k].x, h4.x, a.x);
                a.y = fmaf(w2[k].y, h4.y, a.y);
                a.z = fmaf(w2[k].z, h4.z, a.z);
                a.w = fmaf(w2[k].w, h4.w, a.w);
            }
            p2v = hh1_part + ((a.x + a.y) + (a.z + a.w));
        }
        sp2[tid] = p2v;
        __syncthreads();

        // ---- P4/5: layer-2 pointwise (tid<64) ----
        if (tid < H2_) {
            const float iv = sigmoidf_(sp2[tid]            + sp2[G2_ + tid]);
            const float fv = sigmoidf_(sp2[H2_ + tid]      + sp2[G2_ + H2_ + tid]);
            const float gv = tanhf_   (sp2[2 * H2_ + tid]  + sp2[G2_ + 2 * H2_ + tid]);
            const float ov = sigmoidf_(sp2[3 * H2_ + tid]  + sp2[G2_ + 3 * H2_ + tid]);
            c2 = fmaf(fv, c2, iv * gv);
            const float h = ov * tanhf_(c2);
            ((float*)sh2)[tid] = h;
            h2seq[t * H2_ + tid] = h;   // fire-and-forget store
        }
        __syncthreads();
    }
}

// ---------------- Kernel C: output head out[t,o] = relu(h2[t]) . W_d[o] + b_d
__global__ void head_kernel(const float* __restrict__ h2seq,
                            const float* __restrict__ W_d,
                            const float* __restrict__ b_d,
                            float* __restrict__ out)
{
    const int idx = blockIdx.x * blockDim.x + threadIdx.x;
    if (idx >= T_STEPS * OUT_F) return;
    const int t = idx / OUT_F;
    const int o = idx - t * OUT_F;
    const float* hr = h2seq + t * H2_;
    const float* w  = W_d + o * H2_;
    float acc = b_d[o];
#pragma unroll
    for (int j = 0; j < H2_; ++j) acc = fmaf(fmaxf(hr[j], 0.0f), w[j], acc);
    out[idx] = acc;
}

extern "C" void kernel_launch(void* const* d_in, const int* in_sizes, int n_in,
                              void* d_out, int out_size, void* d_ws, size_t ws_size,
                              hipStream_t stream) {
    const float* x     = (const float*)d_in[0];
    const float* W_ih0 = (const float*)d_in[1];
    const float* W_hh0 = (const float*)d_in[2];
    const float* b_ih0 = (const float*)d_in[3];
    const float* b_hh0 = (const float*)d_in[4];
    const float* W_ih1 = (const float*)d_in[5];
    const float* W_hh1 = (const float*)d_in[6];
    const float* b_ih1 = (const float*)d_in[7];
    const float* b_hh1 = (const float*)d_in[8];
    const float* W_d   = (const float*)d_in[9];
    const float* b_d   = (const float*)d_in[10];

    float* out   = (float*)d_out;
    float* xp1   = (float*)d_ws;                // [1024][512] f32 = 2 MB
    float* h2seq = xp1 + (size_t)T_STEPS * G1_; // [1024][64]  f32 = 256 KB

    hipLaunchKernelGGL(xproj_kernel, dim3(T_STEPS), dim3(G1_), 0, stream,
                       x, W_ih0, b_ih0, b_hh0, xp1);
    hipLaunchKernelGGL(lstm_seq_kernel, dim3(1), dim3(512), 0, stream,
                       xp1, W_hh0, W_ih1, W_hh1, b_ih1, b_hh1, h2seq);
    hipLaunchKernelGGL(head_kernel, dim3((T_STEPS * OUT_F + 255) / 256), dim3(256),
                       0, stream, h2seq, W_d, b_d, out);
}

// Round 3
// 5657.769 us; speedup vs baseline: 1.1716x; 1.1716x over previous
//
#include <hip/hip_runtime.h>
#include <hip/hip_bf16.h>

// Problem: 2-layer LSTM (T=1024, B=512, IN=20, H1=128, H2=64) + linear head OUT=3.
// KEY: reference takes h2[:, -1, :] => only batch element 511 matters.
// Single-CU sequential scan with all recurrent weights resident in VGPRs.
//
// Round-3 fix: float4 ARRAYS (wa[32], w2[24]) were never promoted to registers
// (SROA runs before full unroll -> variable indices -> alloca stays in scratch;
// VGPR_Count=128 and ~790KB/step scratch reloads from L2 = 6.6us/step).
// Replace arrays with 56 NAMED float4 locals via repetition macros -> SSA.

#define T_STEPS 1024
#define BATCH   512
#define IN_F    20
#define H1_     128
#define H2_     64
#define OUT_F   3
#define G1_     (4*H1_)   // 512 layer-1 gates
#define G2_     (4*H2_)   // 256 layer-2 gates

__device__ __forceinline__ float sigmoidf_(float x) {
    return 1.0f / (1.0f + __expf(-x));
}
// tanh(x) = 1 - 2/(exp(2x)+1); stable at +-inf via exp overflow->inf / underflow->0
__device__ __forceinline__ float tanhf_(float x) {
    return 1.0f - 2.0f / (__expf(2.0f * x) + 1.0f);
}

// repetition helpers (constant indices everywhere -> trivially SSA-promotable)
#define REP8(M)  M(0) M(1) M(2) M(3) M(4) M(5) M(6) M(7)
#define REP16(M) REP8(M) M(8) M(9) M(10) M(11) M(12) M(13) M(14) M(15)
#define REP32(M) REP16(M) M(16) M(17) M(18) M(19) M(20) M(21) M(22) M(23) \
                          M(24) M(25) M(26) M(27) M(28) M(29) M(30) M(31)

// ---------------- Kernel A: x-projection for batch row 511 -------------------
__global__ void xproj_kernel(const float* __restrict__ x,
                             const float* __restrict__ W_ih0,
                             const float* __restrict__ b_ih0,
                             const float* __restrict__ b_hh0,
                             float* __restrict__ xp1)
{
    const int t = blockIdx.x;
    const int g = threadIdx.x;
    const float* xr = x + ((size_t)t * BATCH + (BATCH - 1)) * IN_F;
    const float* w  = W_ih0 + g * IN_F;
    float acc = b_ih0[g] + b_hh0[g];
#pragma unroll
    for (int i = 0; i < IN_F; ++i) acc = fmaf(xr[i], w[i], acc);
    xp1[t * G1_ + g] = acc;
}

// ---------------- Kernel B: sequential 2-layer LSTM scan, 1 block ------------
// 512 threads (8 waves). Per thread, register-resident weights:
//   wa0..wa31  : W_hh0 row `tid` (128 floats -> 128 VGPRs)
//   w2a0..7 + w2b0..15 : layer-2 slice (96 floats -> 96 VGPRs)
//     tid <  256 (gate g=tid):  w2a = W_ih1[g][0:32),  w2b = W_ih1[g][32:96)
//     tid >= 256 (gate g=tid-256): w2a = W_ih1[g][96:128), w2b = W_hh1[g][0:64)
// LDS state: scomb[0..31]=h1 quads, scomb[32..47]=h2 quads; sg1 gates; sp2 partials.
__global__ __attribute__((amdgpu_flat_work_group_size(512, 512),
                          amdgpu_waves_per_eu(2, 2)))
void lstm_seq_kernel(const float* __restrict__ xp1,
                     const float* __restrict__ W_hh0,
                     const float* __restrict__ W_ih1,
                     const float* __restrict__ W_hh1,
                     const float* __restrict__ b_ih1,
                     const float* __restrict__ b_hh1,
                     float* __restrict__ h2seq)
{
    const int tid = threadIdx.x;

    __shared__ float4 scomb[48];      // [0..31]=h1, [32..47]=h2
    __shared__ float  sg1[G1_];       // activated layer-1 gates
    __shared__ float  sp2[2 * G2_];   // layer-2 gate partial sums

    // ---- resident weights: NAMED float4 locals (never arrays!) ----
    const float4* pa = (const float4*)(W_hh0 + tid * H1_);
#define DECL_WA(k) float4 wa##k = pa[k];
    REP32(DECL_WA)
#undef DECL_WA

    const bool lowhalf = (tid < G2_);
    const int  o = lowhalf ? tid : (tid - G2_);
    const float4* p1 = lowhalf ? (const float4*)(W_ih1 + o * H1_)
                               : (const float4*)(W_ih1 + o * H1_ + 96);
    const float4* p2 = lowhalf ? ((const float4*)(W_ih1 + o * H1_)) + 8
                               : (const float4*)(W_hh1 + o * H2_);
#define DECL_W2A(k) float4 w2a##k = p1[k];
    REP8(DECL_W2A)
#undef DECL_W2A
#define DECL_W2B(k) float4 w2b##k = p2[k];
    REP16(DECL_W2B)
#undef DECL_W2B

    float extra = 0.0f;               // bias for low half; 0 for high half
    if (lowhalf) extra = b_ih1[tid] + b_hh1[tid];

    // P3 reads scomb[base .. base+23]: low half -> h1[0:96); high -> h1[96:128)+h2
    const float4* sc = scomb + (lowhalf ? 0 : 24);

    // ---- init state ----
    if (tid < 48) scomb[tid] = float4{0, 0, 0, 0};
    float c1 = 0.0f;       // owned by tid < 128
    float c2 = 0.0f;       // owned by tid < 64
    __syncthreads();

    float xp_next = xp1[tid];   // prefetch t=0

    for (int t = 0; t < T_STEPS; ++t) {
        const float xp_cur = xp_next;
        {   // branchless prefetch of next step's x-projection
            const int tn = (t + 1 < T_STEPS) ? (t + 1) : (T_STEPS - 1);
            xp_next = xp1[tn * G1_ + tid];
        }

        // ---- P1: layer-1 gate tid = xp + W_hh0[tid] . h1_old , activated ----
        float ax = 0.0f, ay = 0.0f, az = 0.0f, aw = 0.0f;
#define P1_STEP(k) { const float4 h4 = scomb[k];          \
        ax = fmaf(wa##k.x, h4.x, ax);                     \
        ay = fmaf(wa##k.y, h4.y, ay);                     \
        az = fmaf(wa##k.z, h4.z, az);                     \
        aw = fmaf(wa##k.w, h4.w, aw); }
        REP32(P1_STEP)
#undef P1_STEP
        const float gate = xp_cur + ((ax + ay) + (az + aw));
        // gate order i,f,g,o: i,f,o -> sigmoid ; g -> tanh (wave-uniform branch)
        const float act = (tid < 2 * H1_ || tid >= 3 * H1_) ? sigmoidf_(gate)
                                                            : tanhf_(gate);
        sg1[tid] = act;
        __syncthreads();   // B1: sg1 ready (also orders prev P4's h2 writes)

        // ---- P2: layer-1 pointwise (tid<128) -> h1_new into scomb[0..31] ----
        if (tid < H1_) {
            const float iv = sg1[tid];
            const float fv = sg1[H1_ + tid];
            const float gv = sg1[2 * H1_ + tid];
            const float ov = sg1[3 * H1_ + tid];
            c1 = fmaf(fv, c1, iv * gv);
            const float h = ov * tanhf_(c1);
            ((float*)scomb)[tid] = h;
        }
        __syncthreads();   // B2: h1_new ready

        // ---- P3: layer-2 gate partials (uniform 24-quad dot) ----
        // low half : extra(bias) + W_ih1[g][0:96) . h1_new[0:96)
        // high half: W_ih1[g][96:128) . h1_new[96:128) + W_hh1[g] . h2_old
        {
            float bx = 0.0f, by = 0.0f, bz = 0.0f, bw = 0.0f;
#define P3_A(k) { const float4 h4 = sc[k];                 \
            bx = fmaf(w2a##k.x, h4.x, bx);                \
            by = fmaf(w2a##k.y, h4.y, by);                \
            bz = fmaf(w2a##k.z, h4.z, bz);                \
            bw = fmaf(w2a##k.w, h4.w, bw); }
            REP8(P3_A)
#undef P3_A
#define P3_B(k) { const float4 h4 = sc[8 + k];            \
            bx = fmaf(w2b##k.x, h4.x, bx);                \
            by = fmaf(w2b##k.y, h4.y, by);                \
            bz = fmaf(w2b##k.z, h4.z, bz);                \
            bw = fmaf(w2b##k.w, h4.w, bw); }
            REP16(P3_B)
#undef P3_B
            sp2[tid] = extra + ((bx + by) + (bz + bw));
        }
        __syncthreads();   // B3: sp2 ready

        // ---- P4: layer-2 pointwise (tid<64) -> h2_new, h2seq store ----
        // No trailing barrier: next P1 touches only scomb[0..31]/sg1/xp; B1
        // orders these h2 writes before the next P3 reads them.
        if (tid < H2_) {
            const float iv = sigmoidf_(sp2[tid]           + sp2[G2_ + tid]);
            const float fv = sigmoidf_(sp2[H2_ + tid]     + sp2[G2_ + H2_ + tid]);
            const float gv = tanhf_   (sp2[2 * H2_ + tid] + sp2[G2_ + 2 * H2_ + tid]);
            const float ov = sigmoidf_(sp2[3 * H2_ + tid] + sp2[G2_ + 3 * H2_ + tid]);
            c2 = fmaf(fv, c2, iv * gv);
            const float h = ov * tanhf_(c2);
            ((float*)scomb)[128 + tid] = h;
            h2seq[t * H2_ + tid] = h;   // fire-and-forget store
        }
    }
}

// ---------------- Kernel C: output head out[t,o] = relu(h2[t]) . W_d[o] + b_d
__global__ void head_kernel(const float* __restrict__ h2seq,
                            const float* __restrict__ W_d,
                            const float* __restrict__ b_d,
                            float* __restrict__ out)
{
    const int idx = blockIdx.x * blockDim.x + threadIdx.x;
    if (idx >= T_STEPS * OUT_F) return;
    const int t = idx / OUT_F;
    const int o = idx - t * OUT_F;
    const float* hr = h2seq + t * H2_;
    const float* w  = W_d + o * H2_;
    float acc = b_d[o];
#pragma unroll
    for (int j = 0; j < H2_; ++j) acc = fmaf(fmaxf(hr[j], 0.0f), w[j], acc);
    out[idx] = acc;
}

extern "C" void kernel_launch(void* const* d_in, const int* in_sizes, int n_in,
                              void* d_out, int out_size, void* d_ws, size_t ws_size,
                              hipStream_t stream) {
    const float* x     = (const float*)d_in[0];
    const float* W_ih0 = (const float*)d_in[1];
    const float* W_hh0 = (const float*)d_in[2];
    const float* b_ih0 = (const float*)d_in[3];
    const float* b_hh0 = (const float*)d_in[4];
    const float* W_ih1 = (const float*)d_in[5];
    const float* W_hh1 = (const float*)d_in[6];
    const float* b_ih1 = (const float*)d_in[7];
    const float* b_hh1 = (const float*)d_in[8];
    const float* W_d   = (const float*)d_in[9];
    const float* b_d   = (const float*)d_in[10];

    float* out   = (float*)d_out;
    float* xp1   = (float*)d_ws;                // [1024][512] f32 = 2 MB
    float* h2seq = xp1 + (size_t)T_STEPS * G1_; // [1024][64]  f32 = 256 KB

    hipLaunchKernelGGL(xproj_kernel, dim3(T_STEPS), dim3(G1_), 0, stream,
                       x, W_ih0, b_ih0, b_hh0, xp1);
    hipLaunchKernelGGL(lstm_seq_kernel, dim3(1), dim3(512), 0, stream,
                       xp1, W_hh0, W_ih1, W_hh1, b_ih1, b_hh1, h2seq);
    hipLaunchKernelGGL(head_kernel, dim3((T_STEPS * OUT_F + 255) / 256), dim3(256),
                       0, stream, h2seq, W_d, b_d, out);
}

// Round 4
// 3678.918 us; speedup vs baseline: 1.8018x; 1.5379x over previous
//
#include <hip/hip_runtime.h>
#include <hip/hip_bf16.h>

// Problem: 2-layer LSTM (T=1024, B=512, IN=20, H1=128, H2=64) + head OUT=3.
// KEY: reference takes h2[:, -1, :] => only batch element 511 matters.
//
// Round-4 redesign: 512-thread version demanded ~250 VGPRs -> RA rematerialized
// ALL weight loads inside the loop (VGPR_Count stuck at 128, ~448KB/step L2
// traffic, 5.5us/step). New shape: 1024 threads (16 waves, 4 waves/EU, 128-reg
// tier). Per-thread resident weights = 112 f32:
//   L1: thread owns gate-rows {2rp, 2rp+1}, cols [32cb,32cb+32)  -> 64 regs
//       (cb = tid>>8 wave-uniform, rp = tid&255)
//   L2: thread owns gate g=tid&255, cols [48q,48q+48) of [W_ih1|W_hh1] -> 48
// Gate values assembled via padded LDS partial buffers (stride 5, conflict-free
// reduction reads; L2 bias pre-staged in the pad slot). 3 barriers/step.

#define T_STEPS 1024
#define BATCH   512
#define IN_F    20
#define H1_     128
#define H2_     64
#define OUT_F   3
#define G1_     (4*H1_)   // 512 layer-1 gates
#define G2_     (4*H2_)   // 256 layer-2 gates

__device__ __forceinline__ float sigmoidf_(float x) {
    return 1.0f / (1.0f + __expf(-x));
}
// tanh(x) = 1 - 2/(exp(2x)+1); stable at +-inf via exp overflow/underflow
__device__ __forceinline__ float tanhf_(float x) {
    return 1.0f - 2.0f / (__expf(2.0f * x) + 1.0f);
}

#define REP8(M)  M(0) M(1) M(2) M(3) M(4) M(5) M(6) M(7)
#define REP12(M) REP8(M) M(8) M(9) M(10) M(11)

// ---------------- Kernel A: x-projection for batch row 511 -------------------
__global__ void xproj_kernel(const float* __restrict__ x,
                             const float* __restrict__ W_ih0,
                             const float* __restrict__ b_ih0,
                             const float* __restrict__ b_hh0,
                             float* __restrict__ xp1)
{
    const int t = blockIdx.x;
    const int g = threadIdx.x;
    const float* xr = x + ((size_t)t * BATCH + (BATCH - 1)) * IN_F;
    const float* w  = W_ih0 + g * IN_F;
    float acc = b_ih0[g] + b_hh0[g];
#pragma unroll
    for (int i = 0; i < IN_F; ++i) acc = fmaf(xr[i], w[i], acc);
    xp1[t * G1_ + g] = acc;
}

// ---------------- Kernel B: sequential 2-layer LSTM scan, 1 block ------------
__global__ __attribute__((amdgpu_flat_work_group_size(1024, 1024),
                          amdgpu_waves_per_eu(4, 4)))
void lstm_seq_kernel(const float* __restrict__ xp1,
                     const float* __restrict__ W_hh0,
                     const float* __restrict__ W_ih1,
                     const float* __restrict__ W_hh1,
                     const float* __restrict__ b_ih1,
                     const float* __restrict__ b_hh1,
                     float* __restrict__ h2seq)
{
    const int tid = threadIdx.x;

    __shared__ float4 sc[48];           // [0..31] = h1 (128 f32), [32..47] = h2 (64)
    __shared__ float  sp1[G1_ * 5];     // L1 partials, padded stride 5 (10 KB)
    __shared__ float  sp2[G2_ * 5];     // L2 partials + bias in slot 4 (5 KB)

    const int cb = tid >> 8;            // 0..3, wave-uniform (L1 col-block, L2 quarter)
    const int rp = tid & 255;           // L1 row-pair / L2 gate
    const int q  = cb;
    const int g2 = rp;

    // ---- L1 resident weights: rows {2rp, 2rp+1}, cols [32cb, 32cb+32) ------
    const float4* pr0 = (const float4*)(W_hh0 + (size_t)(2 * rp)     * H1_ + 32 * cb);
    const float4* pr1 = (const float4*)(W_hh0 + (size_t)(2 * rp + 1) * H1_ + 32 * cb);
#define DWA(k) float4 w0_##k = pr0[k]; float4 w1_##k = pr1[k];
    REP8(DWA)
#undef DWA

    // ---- L2 resident weights: gate g2, cols [48q, 48q+48) of [W_ih1 | W_hh1]
    // quarters: q0 -> W_ih1[0:48), q1 -> W_ih1[48:96),
    //           q2 -> W_ih1[96:128) + W_hh1[0:16), q3 -> W_hh1[16:64)
    const int nA = (q <= 1) ? 12 : (q == 2 ? 8 : 0);
    const float4* pA4 = (const float4*)(W_ih1 + (size_t)g2 * H1_ + 48 * q);
    const float4* pB4 = (const float4*)(W_hh1 + (size_t)g2 * H2_ + ((q == 2) ? 0 : 16));
    // select ADDRESS then load (never dereference the unused side)
#define DW2(k) const float4* p2_##k = (k < nA) ? (pA4 + k) : (pB4 + (k - nA)); \
               float4 w2_##k = *p2_##k;
    REP12(DW2)
#undef DW2

    // ---- init: zero state, stage L2 biases into sp2 pad slot ----------------
    if (tid < 48) sc[tid] = float4{0.f, 0.f, 0.f, 0.f};
    if (tid < G2_) sp2[tid * 5 + 4] = b_ih1[tid] + b_hh1[tid];
    float c1 = 0.0f;   // owned by tid < 128
    float c2 = 0.0f;   // owned by tid < 64
    __syncthreads();

    const float4* scp1 = sc + 8 * cb;    // L1 h-slice base
    const float4* scp3 = sc + 12 * q;    // L2 state-slice base

    for (int t = 0; t < T_STEPS; ++t) {
        // ---- P1: L1 partials. cb==0 threads also add xp (2 gates, b64 load).
        float2 xpv = float2{0.f, 0.f};
        if (cb == 0) xpv = *(const float2*)(xp1 + (size_t)t * G1_ + 2 * rp);

        float a0x = 0.f, a0y = 0.f, a0z = 0.f, a0w = 0.f;
        float a1x = 0.f, a1y = 0.f, a1z = 0.f, a1w = 0.f;
#define P1S(k) { const float4 h4 = scp1[k];                                  \
        a0x = fmaf(w0_##k.x, h4.x, a0x); a0y = fmaf(w0_##k.y, h4.y, a0y);    \
        a0z = fmaf(w0_##k.z, h4.z, a0z); a0w = fmaf(w0_##k.w, h4.w, a0w);    \
        a1x = fmaf(w1_##k.x, h4.x, a1x); a1y = fmaf(w1_##k.y, h4.y, a1y);    \
        a1z = fmaf(w1_##k.z, h4.z, a1z); a1w = fmaf(w1_##k.w, h4.w, a1w); }
        REP8(P1S)
#undef P1S
        sp1[(2 * rp)     * 5 + cb] = ((a0x + a0y) + (a0z + a0w)) + xpv.x;
        sp1[(2 * rp + 1) * 5 + cb] = ((a1x + a1y) + (a1z + a1w)) + xpv.y;
        __syncthreads();   // B1: sp1 ready (also orders prev P4's h2 writes)

        // ---- P2 (tid<128): combine 4 partials/gate, activate, h1_new -------
        if (tid < H1_) {
            const float* s = sp1 + tid * 5;
            const float vi = (s[0]    + s[1])    + (s[2]    + s[3]);
            const float vf = (s[640]  + s[641])  + (s[642]  + s[643]);
            const float vg = (s[1280] + s[1281]) + (s[1282] + s[1283]);
            const float vo = (s[1920] + s[1921]) + (s[1922] + s[1923]);
            c1 = fmaf(sigmoidf_(vf), c1, sigmoidf_(vi) * tanhf_(vg));
            const float h = sigmoidf_(vo) * tanhf_(c1);
            ((float*)sc)[tid] = h;
        }
        __syncthreads();   // B2: h1_new ready

        // ---- P3: L2 partials over [h1_new | h2_old] -------------------------
        float bx = 0.f, by = 0.f, bz = 0.f, bw = 0.f;
#define P3S(k) { const float4 h4 = scp3[k];                                  \
        bx = fmaf(w2_##k.x, h4.x, bx); by = fmaf(w2_##k.y, h4.y, by);        \
        bz = fmaf(w2_##k.z, h4.z, bz); bw = fmaf(w2_##k.w, h4.w, bw); }
        REP12(P3S)
#undef P3S
        sp2[g2 * 5 + q] = (bx + by) + (bz + bw);
        __syncthreads();   // B3: sp2 ready

        // ---- P4 (tid<64): combine, activate, h2_new, store ------------------
        // No trailing barrier: next P1 touches only sc[0..31]/sp1/xp; B1 of
        // step t+1 orders these h2/sp2 accesses against next P3.
        if (tid < H2_) {
            const float* s = sp2 + tid * 5;
            const float vi = ((s[0]   + s[1])   + (s[2]   + s[3]))   + s[4];
            const float vf = ((s[320] + s[321]) + (s[322] + s[323])) + s[324];
            const float vg = ((s[640] + s[641]) + (s[642] + s[643])) + s[644];
            const float vo = ((s[960] + s[961]) + (s[962] + s[963])) + s[964];
            c2 = fmaf(sigmoidf_(vf), c2, sigmoidf_(vi) * tanhf_(vg));
            const float h = sigmoidf_(vo) * tanhf_(c2);
            ((float*)sc)[H1_ + tid] = h;
            h2seq[(size_t)t * H2_ + tid] = h;
        }
    }
}

// ---------------- Kernel C: output head out[t,o] = relu(h2[t]) . W_d[o] + b_d
__global__ void head_kernel(const float* __restrict__ h2seq,
                            const float* __restrict__ W_d,
                            const float* __restrict__ b_d,
                            float* __restrict__ out)
{
    const int idx = blockIdx.x * blockDim.x + threadIdx.x;
    if (idx >= T_STEPS * OUT_F) return;
    const int t = idx / OUT_F;
    const int o = idx - t * OUT_F;
    const float* hr = h2seq + t * H2_;
    const float* w  = W_d + o * H2_;
    float acc = b_d[o];
#pragma unroll
    for (int j = 0; j < H2_; ++j) acc = fmaf(fmaxf(hr[j], 0.0f), w[j], acc);
    out[idx] = acc;
}

extern "C" void kernel_launch(void* const* d_in, const int* in_sizes, int n_in,
                              void* d_out, int out_size, void* d_ws, size_t ws_size,
                              hipStream_t stream) {
    const float* x     = (const float*)d_in[0];
    const float* W_ih0 = (const float*)d_in[1];
    const float* W_hh0 = (const float*)d_in[2];
    const float* b_ih0 = (const float*)d_in[3];
    const float* b_hh0 = (const float*)d_in[4];
    const float* W_ih1 = (const float*)d_in[5];
    const float* W_hh1 = (const float*)d_in[6];
    const float* b_ih1 = (const float*)d_in[7];
    const float* b_hh1 = (const float*)d_in[8];
    const float* W_d   = (const float*)d_in[9];
    const float* b_d   = (const float*)d_in[10];

    float* out   = (float*)d_out;
    float* xp1   = (float*)d_ws;                // [1024][512] f32 = 2 MB
    float* h2seq = xp1 + (size_t)T_STEPS * G1_; // [1024][64]  f32 = 256 KB

    hipLaunchKernelGGL(xproj_kernel, dim3(T_STEPS), dim3(G1_), 0, stream,
                       x, W_ih0, b_ih0, b_hh0, xp1);
    hipLaunchKernelGGL(lstm_seq_kernel, dim3(1), dim3(1024), 0, stream,
                       xp1, W_hh0, W_ih1, W_hh1, b_ih1, b_hh1, h2seq);
    hipLaunchKernelGGL(head_kernel, dim3((T_STEPS * OUT_F + 255) / 256), dim3(256),
                       0, stream, h2seq, W_d, b_d, out);
}